// Round 4
// baseline (110.556 us; speedup 1.0000x reference)
//
#include <hip/hip_runtime.h>
#include <math.h>

#define HID 50
#define NPTS 8192
#define NPARA 5000
#define NLAYERS 4

#define BLOCK 1024
#define WPB   16           // waves per block
#define GRID  512          // GRID*WPB = 8192 waves = 1 wave per point, all resident

// Weight LDS arrays padded so lanes 50..63 read in-bounds (values finite,
// never broadcast, masked at the output reduction).
#define SWIN_SZ (3*HID + 16)
#define SBIN_SZ (HID + 16)
#define SWH_SZ  (NLAYERS*HID*HID + 16)
#define SBH_SZ  (NLAYERS*HID + 16)
#define SWO_SZ  (2*64)

__device__ __forceinline__ float fast_tanh(float x) {
    const float ax = __builtin_fabsf(x);
    const float e  = __expf(2.0f * ax);
    const float r  = __builtin_amdgcn_rcpf(e + 1.0f);
    const float t  = fmaf(-2.0f, r, 1.0f);
    return __builtin_copysignf(t, x);
}

// Broadcast lane k's value to all lanes via the VALU (v_readlane -> SGPR),
// k is a literal after full unroll. Avoids the LDS pipe entirely.
__device__ __forceinline__ float readlane_f(float v, int k) {
    return __int_as_float(__builtin_amdgcn_readlane(__float_as_int(v), k));
}

__global__ __launch_bounds__(BLOCK, 8) void point_kernel(
    const float* __restrict__ x,
    const float* __restrict__ W_in, const float* __restrict__ b_in,
    const float* __restrict__ W_hid, const float* __restrict__ b_hid,
    const float* __restrict__ W_out, const float* __restrict__ b_out,
    double* __restrict__ part, int use_atomic)
{
    __shared__ float sWin[SWIN_SZ];
    __shared__ float sbin[SBIN_SZ];
    __shared__ float sWh[SWH_SZ];
    __shared__ float sbh[SBH_SZ];
    __shared__ float sWo[SWO_SZ];
    __shared__ float sbo[2];
    __shared__ double sRed[WPB][6];

    const int tid = threadIdx.x;
    for (int i = tid; i < 3*HID; i += BLOCK) sWin[i] = W_in[i];
    for (int i = 3*HID + tid; i < SWIN_SZ; i += BLOCK) sWin[i] = 0.f;
    for (int i = tid; i < HID; i += BLOCK) sbin[i] = b_in[i];
    for (int i = HID + tid; i < SBIN_SZ; i += BLOCK) sbin[i] = 0.f;
    for (int i = tid; i < NLAYERS*HID*HID; i += BLOCK) sWh[i] = W_hid[i];
    for (int i = NLAYERS*HID*HID + tid; i < SWH_SZ; i += BLOCK) sWh[i] = 0.f;
    for (int i = tid; i < NLAYERS*HID; i += BLOCK) sbh[i] = b_hid[i];
    for (int i = NLAYERS*HID + tid; i < SBH_SZ; i += BLOCK) sbh[i] = 0.f;
    for (int i = tid; i < 2*HID; i += BLOCK) sWo[i] = W_out[i];
    for (int i = 2*HID + tid; i < SWO_SZ; i += BLOCK) sWo[i] = 0.f;
    if (tid < 2) sbo[tid] = b_out[tid];
    __syncthreads();

    const int lane = tid & 63;
    const int wave = tid >> 6;
    const int p    = blockIdx.x * WPB + wave;   // one point per wave, p < 8192

    // x index is wave-uniform -> scalar loads
    const float x0 = x[3*p+0], x1 = x[3*p+1], x2 = x[3*p+2];

    // ---- input layer ----
    const float w0 = sWin[lane];
    const float w1 = sWin[HID + lane];
    const float w2 = sWin[2*HID + lane];
    float z = fmaf(x0, w0, fmaf(x1, w1, fmaf(x2, w2, sbin[lane])));
    float h = fast_tanh(z);
    float s = 1.f - h*h;
    float hx = s*w0, hy = s*w1, ht = s*w2;
    float hxx = -2.f*h*s*w0*w0;
    float hyy = -2.f*h*s*w1*w1;

    // ---- hidden layers ----
    for (int l = 0; l < NLAYERS; ++l) {
        const float* __restrict__ Wl = &sWh[l*HID*HID];
        float za  = sbh[l*HID + lane];
        float zx = 0.f, zy = 0.f, zt = 0.f, zxx = 0.f, zyy = 0.f;
        #pragma unroll
        for (int k = 0; k < HID; ++k) {
            const float w = Wl[k*HID + lane];   // lane-strided ds_read_b32, conflict-free
            za  = fmaf(readlane_f(h,   k), w, za);
            zx  = fmaf(readlane_f(hx,  k), w, zx);
            zy  = fmaf(readlane_f(hy,  k), w, zy);
            zt  = fmaf(readlane_f(ht,  k), w, zt);
            zxx = fmaf(readlane_f(hxx, k), w, zxx);
            zyy = fmaf(readlane_f(hyy, k), w, zyy);
        }
        const float hn = fast_tanh(za);
        const float sn = 1.f - hn*hn;
        hxx = fmaf(sn, zxx, -2.f*hn*sn*zx*zx);
        hyy = fmaf(sn, zyy, -2.f*hn*sn*zy*zy);
        hx = sn*zx; hy = sn*zy; ht = sn*zt;
        h = hn;
    }

    // ---- output layer partials + wave reduction ----
    const float wo0 = sWo[lane*2+0];
    const float wo1 = sWo[lane*2+1];
    const bool act = (lane < HID);
    float pu   = act ? h  *wo0 : 0.f;
    float pv   = act ? h  *wo1 : 0.f;
    float put  = act ? ht *wo0 : 0.f;
    float pvt  = act ? ht *wo1 : 0.f;
    float puxx = act ? hxx*wo0 : 0.f;
    float pvxx = act ? hxx*wo1 : 0.f;
    float puyy = act ? hyy*wo0 : 0.f;
    float pvyy = act ? hyy*wo1 : 0.f;
    #pragma unroll
    for (int off = 32; off > 0; off >>= 1) {
        pu   += __shfl_xor(pu,   off);
        pv   += __shfl_xor(pv,   off);
        put  += __shfl_xor(put,  off);
        pvt  += __shfl_xor(pvt,  off);
        puxx += __shfl_xor(puxx, off);
        pvxx += __shfl_xor(pvxx, off);
        puyy += __shfl_xor(puyy, off);
        pvyy += __shfl_xor(pvyy, off);
    }
    const float u = pu + sbo[0];
    const float v = pv + sbo[1];
    const float Q = u*u + v*v;
    const float g1 = pvt - 0.5f*puxx - 0.5f*pvyy - Q*u + v;   // base1
    const float g2 = put + 0.5f*pvxx - 0.5f*puyy + Q*v + u;   // base2
    const float h1 = 0.5f*puyy, h2 = 0.5f*pvyy;
    const float k1 = Q*v,       k2 = Q*u;

    // f1 = g1 - a*h1 - cc*k1 ; f2 = g2 + a*h2 - cc*k2
    // mean(f1^2+f2^2) = (S0 + a^2 S1 + cc^2 S2 + 2a S3 - 2cc S4 + 2a cc S5)/N
    const double a0 = (double)g1*(double)g1 + (double)g2*(double)g2;
    const double a1 = (double)h1*(double)h1 + (double)h2*(double)h2;
    const double a2 = (double)k1*(double)k1 + (double)k2*(double)k2;
    const double a3 = (double)g2*(double)h2 - (double)g1*(double)h1;
    const double a4 = (double)g1*(double)k1 + (double)g2*(double)k2;
    const double a5 = (double)h1*(double)k1 - (double)h2*(double)k2;

    // ---- block-level reduction, then ONE store (or atomic) set per block ----
    if (lane == 0) {
        sRed[wave][0] = a0; sRed[wave][1] = a1; sRed[wave][2] = a2;
        sRed[wave][3] = a3; sRed[wave][4] = a4; sRed[wave][5] = a5;
    }
    __syncthreads();
    if (tid < 6) {
        double t = 0.0;
        #pragma unroll
        for (int wv = 0; wv < WPB; ++wv) t += sRed[wv][tid];
        if (use_atomic) atomicAdd(&part[tid], t);
        else            part[blockIdx.x * 6 + tid] = t;
    }
}

__global__ __launch_bounds__(512) void para_kernel(
    const float* __restrict__ para,
    const double* __restrict__ part, int nsets,
    float* __restrict__ out)
{
    __shared__ double sW[8][6];
    __shared__ double sS[6];
    const int tid  = threadIdx.x;
    const int lane = tid & 63;
    const int wave = tid >> 6;

    // reduce nsets x 6 partials (nsets = GRID for store path, 1 for atomic path)
    double c0=0,c1=0,c2=0,c3=0,c4=0,c5=0;
    for (int i = tid; i < nsets; i += 512) {
        const double* q = &part[i*6];
        c0 += q[0]; c1 += q[1]; c2 += q[2]; c3 += q[3]; c4 += q[4]; c5 += q[5];
    }
    #pragma unroll
    for (int off = 32; off > 0; off >>= 1) {
        c0 += __shfl_xor(c0, off); c1 += __shfl_xor(c1, off);
        c2 += __shfl_xor(c2, off); c3 += __shfl_xor(c3, off);
        c4 += __shfl_xor(c4, off); c5 += __shfl_xor(c5, off);
    }
    if (lane == 0) {
        sW[wave][0]=c0; sW[wave][1]=c1; sW[wave][2]=c2;
        sW[wave][3]=c3; sW[wave][4]=c4; sW[wave][5]=c5;
    }
    __syncthreads();
    if (tid < 6) {
        double t = 0.0;
        #pragma unroll
        for (int wv = 0; wv < 8; ++wv) t += sW[wv][tid];
        sS[tid] = t;
    }
    __syncthreads();

    const double S0=sS[0], S1=sS[1], S2=sS[2], S3=sS[3], S4=sS[4], S5=sS[5];
    for (int p = blockIdx.x * 512 + tid; p < NPARA; p += gridDim.x * 512) {
        const double a  = (double)para[3*p+0];
        const double cc = (double)para[3*p+2];
        const double r = S0 + a*a*S1 + cc*cc*S2 + 2.0*a*S3 - 2.0*cc*S4 + 2.0*a*cc*S5;
        out[p] = (float)(r * (1.0 / (double)NPTS));
    }
}

extern "C" void kernel_launch(void* const* d_in, const int* in_sizes, int n_in,
                              void* d_out, int out_size, void* d_ws, size_t ws_size,
                              hipStream_t stream) {
    const float* x     = (const float*)d_in[0];
    const float* para  = (const float*)d_in[1];
    const float* W_in  = (const float*)d_in[2];
    const float* b_in  = (const float*)d_in[3];
    const float* W_hid = (const float*)d_in[4];
    const float* b_hid = (const float*)d_in[5];
    const float* W_out = (const float*)d_in[6];
    const float* b_out = (const float*)d_in[7];
    double* part = (double*)d_ws;

    const bool store_path = (ws_size >= (size_t)GRID * 6 * sizeof(double));
    if (store_path) {
        // no-init path: plain per-block stores, 2 graph nodes total
        point_kernel<<<GRID, BLOCK, 0, stream>>>(x, W_in, b_in, W_hid, b_hid,
                                                 W_out, b_out, part, 0);
        para_kernel<<<10, 512, 0, stream>>>(para, part, GRID, (float*)d_out);
    } else {
        hipMemsetAsync(part, 0, 6*sizeof(double), stream);
        point_kernel<<<GRID, BLOCK, 0, stream>>>(x, W_in, b_in, W_hid, b_hid,
                                                 W_out, b_out, part, 1);
        para_kernel<<<10, 512, 0, stream>>>(para, part, 1, (float*)d_out);
    }
}